// Round 5
// baseline (127.525 us; speedup 1.0000x reference)
//
#include <hip/hip_runtime.h>
#include <stdint.h>

typedef unsigned short u16;
typedef __attribute__((ext_vector_type(8))) short bf16x8;
typedef __attribute__((ext_vector_type(4))) short bf16x4;
typedef __attribute__((ext_vector_type(4))) float f32x4;
typedef __attribute__((ext_vector_type(4))) unsigned short u16x4;
typedef __attribute__((ext_vector_type(2))) unsigned u32x2;

#define S_ 2048
#define E_ 1024
// 0.125 (1/sqrt(64)) * log2(e): folds softmax scale + exp->exp2 into Q
#define QSCALE 0.18033688011112042f

__device__ __forceinline__ u16 f2bf(float f) {
  union { float f; unsigned u; } v; v.f = f;
  unsigned u = v.u;
  unsigned r = (u + 0x7FFFu + ((u >> 16) & 1u)) >> 16;
  return (u16)r;
}
__device__ __forceinline__ float bf2f(u16 h) {
  union { unsigned u; float f; } v; v.u = ((unsigned)h) << 16;
  return v.f;
}
__device__ __forceinline__ unsigned cvtpk(float a, float b) {
  unsigned r;
  asm("v_cvt_pk_bf16_f32 %0, %1, %2" : "=v"(r) : "v"(a), "v"(b));
  return r;
}
__device__ __forceinline__ bf16x4 pk4(float a, float b, float c, float d) {
  union { u32x2 u; bf16x4 v; } U;
  U.u[0] = cvtpk(a, b);
  U.u[1] = cvtpk(c, d);
  return U.v;
}

typedef __attribute__((address_space(3))) void lds_void;
__device__ __forceinline__ unsigned lds_off(void* p) {
  return (unsigned)(unsigned long long)(lds_void*)p;
}
__device__ __forceinline__ void glds16(const u16* g, u16* l) {
  __builtin_amdgcn_global_load_lds(
      (const __attribute__((address_space(1))) void*)g,
      (__attribute__((address_space(3))) void*)l, 16, 0, 0);
}

// ---------------- fused cast f32 -> bf16 for all 5 inputs ----------------
__global__ void k_cast5(const float* __restrict__ x,
                        const float* __restrict__ wq, const float* __restrict__ wk,
                        const float* __restrict__ wv, const float* __restrict__ wo,
                        u16* __restrict__ xb, u16* __restrict__ wqb, u16* __restrict__ wkb,
                        u16* __restrict__ wvb, u16* __restrict__ wob) {
  int i = blockIdx.x * blockDim.x + threadIdx.x;
  const float* src; u16* dst; int off;
  if (i < 1048576) { src = x; dst = xb; off = i; }
  else {
    int j = i - 1048576;
    int w = j >> 18; off = j & 262143;
    src = (w == 0) ? wq : (w == 1) ? wk : (w == 2) ? wv : wo;
    dst = (w == 0) ? wqb : (w == 1) ? wkb : (w == 2) ? wvb : wob;
  }
  float4 v = *((const float4*)src + off);
  u16x4 o;
  o.x = f2bf(v.x); o.y = f2bf(v.y); o.z = f2bf(v.z); o.w = f2bf(v.w);
  *((u16x4*)dst + off) = o;
}

// ---------------- 128x128 tile bf16 GEMM, 2-phase double-buffered LDS ----------------
__global__ __launch_bounds__(256) void k_gemm(
    const u16* __restrict__ A,
    const u16* __restrict__ W0, const u16* __restrict__ W1, const u16* __restrict__ W2,
    void* O0, void* O1, void* O2, int outF32)
{
  __shared__ __align__(16) u16 As[2][128 * 32];
  __shared__ __align__(16) u16 Ws[2][128 * 32];
  int tid = threadIdx.x;
  int wid = tid >> 6, lane = tid & 63;
  int lg = lane >> 4, lr = lane & 15;
  int wsel = blockIdx.y >> 3, nb = blockIdx.y & 7;
  const u16* W = (wsel == 0) ? W0 : ((wsel == 1) ? W1 : W2);
  void* O = (wsel == 0) ? O0 : ((wsel == 1) ? O1 : O2);
  int m0 = blockIdx.x * 128;
  int n0 = nb * 128;
  int wr = wid >> 1, wc = wid & 1;

  f32x4 acc[4][4];
#pragma unroll
  for (int m = 0; m < 4; m++)
#pragma unroll
    for (int n = 0; n < 4; n++) acc[m][n] = (f32x4){0.f, 0.f, 0.f, 0.f};

  int srow = tid >> 2;
  int schunk = (tid & 3) ^ ((tid >> 3) & 3);
  const u16* ag = A + (size_t)(m0 + srow) * 1024 + schunk * 8;
  const u16* wg = W + (size_t)(n0 + srow) * 1024 + schunk * 8;

  int buf = 0;
  glds16(ag, &As[0][tid * 8]);
  glds16(ag + 65536, &As[0][tid * 8 + 2048]);
  glds16(wg, &Ws[0][tid * 8]);
  glds16(wg + 65536, &Ws[0][tid * 8 + 2048]);
  __syncthreads();

  for (int kt = 0; kt < 1024; kt += 32) {
    if (kt + 32 < 1024) {
      glds16(ag + kt + 32, &As[buf ^ 1][tid * 8]);
      glds16(ag + kt + 32 + 65536, &As[buf ^ 1][tid * 8 + 2048]);
      glds16(wg + kt + 32, &Ws[buf ^ 1][tid * 8]);
      glds16(wg + kt + 32 + 65536, &Ws[buf ^ 1][tid * 8 + 2048]);
    }
    bf16x8 af[4], wf[4];
#pragma unroll
    for (int m = 0; m < 4; m++) {
      int row = wr * 64 + m * 16 + lr;
      af[m] = *(const bf16x8*)&As[buf][row * 32 + ((lg ^ ((row >> 1) & 3)) * 8)];
    }
#pragma unroll
    for (int n = 0; n < 4; n++) {
      int row = wc * 64 + n * 16 + lr;
      wf[n] = *(const bf16x8*)&Ws[buf][row * 32 + ((lg ^ ((row >> 1) & 3)) * 8)];
    }
    __builtin_amdgcn_s_setprio(1);
#pragma unroll
    for (int m = 0; m < 4; m++)
#pragma unroll
      for (int n = 0; n < 4; n++)
        acc[m][n] = __builtin_amdgcn_mfma_f32_16x16x32_bf16(af[m], wf[n], acc[m][n], 0, 0, 0);
    __builtin_amdgcn_s_setprio(0);
    __syncthreads();
    buf ^= 1;
  }

#pragma unroll
  for (int m = 0; m < 4; m++) {
    int gr = m0 + wr * 64 + m * 16 + lg * 4;
#pragma unroll
    for (int n = 0; n < 4; n++) {
      int gc = n0 + wc * 64 + n * 16 + lr;
#pragma unroll
      for (int r = 0; r < 4; r++) {
        if (outF32) ((float*)O)[(size_t)(gr + r) * 1024 + gc] = acc[m][n][r];
        else ((u16*)O)[(size_t)(gr + r) * 1024 + gc] = f2bf(acc[m][n][r]);
      }
    }
  }
}

// ---------------- RoPE in place; Q additionally scaled by QSCALE ----------------
__global__ void k_rope(u16* __restrict__ Q, u16* __restrict__ K) {
  int idx = blockIdx.x * blockDim.x + threadIdx.x;
  int p = idx & 511;
  int srow = idx >> 9;
  int s = srow & (S_ - 1);
  int i = p & 31;
  float ang = (float)s * exp2f(-0.415241012f * (float)i);
  float sn, c;
  __sincosf(ang, &sn, &c);
  unsigned* qp = (unsigned*)Q + idx;
  unsigned qv = *qp;
  float e = bf2f((u16)(qv & 0xffff)), o = bf2f((u16)(qv >> 16));
  float re = (e * c - o * sn) * QSCALE, ro = (e * sn + o * c) * QSCALE;
  *qp = cvtpk(re, ro);
  unsigned* kp = (unsigned*)K + idx;
  unsigned kv = *kp;
  e = bf2f((u16)(kv & 0xffff)); o = bf2f((u16)(kv >> 16));
  re = e * c - o * sn; ro = e * sn + o * c;
  *kp = cvtpk(re, ro);
}

// ---------------- causal flash attention, KVBLK=64, QBLK=32/wave ----------------
// grid: x = bh, y = q-block (128 rows). 4 waves; wave owns q rows [q0, q0+32)
// as two 16-row subgroups a,b. Each staged K/V fragment feeds 2 MFMAs.
__global__ __launch_bounds__(256) void k_attn(
    const u16* __restrict__ Q, const u16* __restrict__ K,
    const u16* __restrict__ V, u16* __restrict__ AO)
{
  __shared__ __align__(16) u16 Ks[64 * 64];
  __shared__ __align__(16) u16 Vs[64 * 64];
  int tid = threadIdx.x;
  int wid = tid >> 6, lane = tid & 63;
  int lg = lane >> 4, lr = lane & 15;
  int bh = blockIdx.x;
  int qb = 15 - (int)blockIdx.y;
  int q0 = qb * 128 + wid * 32;
  size_t base = (size_t)(bh >> 4) * (2048u * 1024u) + (size_t)(bh & 15) * 64;

  const u16* qrow = Q + base + (size_t)(q0 + lr) * 1024 + lg * 8;
  bf16x8 qf0a = *(const bf16x8*)(qrow);
  bf16x8 qf1a = *(const bf16x8*)(qrow + 32);
  bf16x8 qf0b = *(const bf16x8*)(qrow + 16 * 1024);
  bf16x8 qf1b = *(const bf16x8*)(qrow + 16 * 1024 + 32);

  int srow = tid >> 3;
  int sch = tid & 7;
  const u16* kg = K + base + (size_t)srow * 1024 + sch * 8;
  const u16* vg = V + base + (size_t)srow * 1024 + sch * 8;
  int kwb0 = ((srow)*128 + sch * 16) ^ ((srow & 7) << 4);
  int kwb1 = ((srow + 32) * 128 + sch * 16) ^ ((srow & 7) << 4);
  int vwi0 = (srow >> 4) * 1024 + (sch >> 1) * 256 + (srow & 15) * 16 + (sch & 1) * 8;
  int vwi1 = ((srow + 32) >> 4) * 1024 + (sch >> 1) * 256 + (srow & 15) * 16 + (sch & 1) * 8;

  bf16x8 kr0 = *(const bf16x8*)(kg);
  bf16x8 kr1 = *(const bf16x8*)(kg + 32 * 1024);
  bf16x8 vr0 = *(const bf16x8*)(vg);
  bf16x8 vr1 = *(const bf16x8*)(vg + 32 * 1024);
  const u16* kgp = kg + 64 * 1024;
  const u16* vgp = vg + 64 * 1024;

  float ma = -1e30f, mb = -1e30f, lsa = 0.f, lsb = 0.f;
  f32x4 oa[4], ob[4];
#pragma unroll
  for (int c = 0; c < 4; c++) {
    oa[c] = (f32x4){0.f, 0.f, 0.f, 0.f};
    ob[c] = (f32x4){0.f, 0.f, 0.f, 0.f};
  }

  int qga = q0 + lr;
  int qgb = q0 + 16 + lr;
  int ntw = (q0 >> 6) + 1;            // tiles this wave computes (last is masked)
  int ntb = 2 * qb + 2;               // block loop bound (wave 3's ntw)
  unsigned vrd = lds_off(Vs) + (unsigned)(lane * 8);

  for (int t = 0; t < ntb; ++t) {
    __syncthreads();
    *(bf16x8*)((char*)Ks + kwb0) = kr0;
    *(bf16x8*)((char*)Ks + kwb1) = kr1;
    *(bf16x8*)(&Vs[vwi0]) = vr0;
    *(bf16x8*)(&Vs[vwi1]) = vr1;
    __syncthreads();
    if (t + 1 < ntb) {
      kr0 = *(const bf16x8*)(kgp);
      kr1 = *(const bf16x8*)(kgp + 32 * 1024);
      vr0 = *(const bf16x8*)(vgp);
      vr1 = *(const bf16x8*)(vgp + 32 * 1024);
      kgp += 64 * 1024;
      vgp += 64 * 1024;
    }
    if (t >= ntw) continue;  // wave done; still participates in barriers/staging

    f32x4 sa[4], sb[4];
    int kv0 = t * 64;
    __builtin_amdgcn_s_setprio(1);
#pragma unroll
    for (int sub = 0; sub < 4; ++sub) {
      int row = sub * 16 + lr;
      int swz = (row & 7) << 4;
      bf16x8 kf0 = *(const bf16x8*)((const char*)Ks + ((row * 128 + lg * 16) ^ swz));
      bf16x8 kf1 = *(const bf16x8*)((const char*)Ks + ((row * 128 + 64 + lg * 16) ^ swz));
      f32x4 z = (f32x4){0.f, 0.f, 0.f, 0.f};
      z = __builtin_amdgcn_mfma_f32_16x16x32_bf16(kf0, qf0a, z, 0, 0, 0);
      sa[sub] = __builtin_amdgcn_mfma_f32_16x16x32_bf16(kf1, qf1a, z, 0, 0, 0);
      f32x4 z2 = (f32x4){0.f, 0.f, 0.f, 0.f};
      z2 = __builtin_amdgcn_mfma_f32_16x16x32_bf16(kf0, qf0b, z2, 0, 0, 0);
      sb[sub] = __builtin_amdgcn_mfma_f32_16x16x32_bf16(kf1, qf1b, z2, 0, 0, 0);
    }
    __builtin_amdgcn_s_setprio(0);
    if (t == ntw - 1) {
#pragma unroll
      for (int sub = 0; sub < 4; ++sub)
#pragma unroll
        for (int j = 0; j < 4; ++j) {
          int kvg = kv0 + sub * 16 + lg * 4 + j;
          sa[sub][j] = (kvg <= qga) ? sa[sub][j] : -1e30f;
          sb[sub][j] = (kvg <= qgb) ? sb[sub][j] : -1e30f;
        }
    }
    float tma = fmaxf(fmaxf(fmaxf(sa[0][0], sa[0][1]), fmaxf(sa[0][2], sa[0][3])),
                      fmaxf(fmaxf(sa[1][0], sa[1][1]), fmaxf(sa[1][2], sa[1][3])));
    tma = fmaxf(tma, fmaxf(fmaxf(fmaxf(sa[2][0], sa[2][1]), fmaxf(sa[2][2], sa[2][3])),
                           fmaxf(fmaxf(sa[3][0], sa[3][1]), fmaxf(sa[3][2], sa[3][3]))));
    float tmb = fmaxf(fmaxf(fmaxf(sb[0][0], sb[0][1]), fmaxf(sb[0][2], sb[0][3])),
                      fmaxf(fmaxf(sb[1][0], sb[1][1]), fmaxf(sb[1][2], sb[1][3])));
    tmb = fmaxf(tmb, fmaxf(fmaxf(fmaxf(sb[2][0], sb[2][1]), fmaxf(sb[2][2], sb[2][3])),
                           fmaxf(fmaxf(sb[3][0], sb[3][1]), fmaxf(sb[3][2], sb[3][3]))));
    tma = fmaxf(tma, __shfl_xor(tma, 16));
    tma = fmaxf(tma, __shfl_xor(tma, 32));
    tmb = fmaxf(tmb, __shfl_xor(tmb, 16));
    tmb = fmaxf(tmb, __shfl_xor(tmb, 32));
    if (!__all((tma <= ma + 8.f) && (tmb <= mb + 8.f))) {
      float mna = fmaxf(ma, tma), mnb = fmaxf(mb, tmb);
      float ca = __builtin_amdgcn_exp2f(ma - mna);
      float cb = __builtin_amdgcn_exp2f(mb - mnb);
      ma = mna; mb = mnb;
      lsa *= ca; lsb *= cb;
#pragma unroll
      for (int c = 0; c < 4; ++c) {
        oa[c][0] *= ca; oa[c][1] *= ca; oa[c][2] *= ca; oa[c][3] *= ca;
        ob[c][0] *= cb; ob[c][1] *= cb; ob[c][2] *= cb; ob[c][3] *= cb;
      }
    }
    bf16x4 pa[4], pb[4];
#pragma unroll
    for (int sub = 0; sub < 4; ++sub) {
      float a0 = __builtin_amdgcn_exp2f(sa[sub][0] - ma);
      float a1 = __builtin_amdgcn_exp2f(sa[sub][1] - ma);
      float a2 = __builtin_amdgcn_exp2f(sa[sub][2] - ma);
      float a3 = __builtin_amdgcn_exp2f(sa[sub][3] - ma);
      lsa += (a0 + a1) + (a2 + a3);
      pa[sub] = pk4(a0, a1, a2, a3);
      float b0 = __builtin_amdgcn_exp2f(sb[sub][0] - mb);
      float b1 = __builtin_amdgcn_exp2f(sb[sub][1] - mb);
      float b2 = __builtin_amdgcn_exp2f(sb[sub][2] - mb);
      float b3 = __builtin_amdgcn_exp2f(sb[sub][3] - mb);
      lsb += (b0 + b1) + (b2 + b3);
      pb[sub] = pk4(b0, b1, b2, b3);
    }
#pragma unroll
    for (int sub = 0; sub < 4; ++sub) {
      unsigned wa = vrd + (unsigned)(sub * 2048);
      bf16x4 va0, va1, va2, va3;
      asm volatile("ds_read_b64_tr_b16 %0, %1" : "=v"(va0) : "v"(wa));
      asm volatile("ds_read_b64_tr_b16 %0, %1 offset:512" : "=v"(va1) : "v"(wa));
      asm volatile("ds_read_b64_tr_b16 %0, %1 offset:1024" : "=v"(va2) : "v"(wa));
      asm volatile("ds_read_b64_tr_b16 %0, %1 offset:1536" : "=v"(va3) : "v"(wa));
      asm volatile("s_waitcnt lgkmcnt(0)" ::: "memory");
      __builtin_amdgcn_sched_barrier(0);
      __builtin_amdgcn_s_setprio(1);
      oa[0] = __builtin_amdgcn_mfma_f32_16x16x16bf16_1k(va0, pa[sub], oa[0], 0, 0, 0);
      oa[1] = __builtin_amdgcn_mfma_f32_16x16x16bf16_1k(va1, pa[sub], oa[1], 0, 0, 0);
      oa[2] = __builtin_amdgcn_mfma_f32_16x16x16bf16_1k(va2, pa[sub], oa[2], 0, 0, 0);
      oa[3] = __builtin_amdgcn_mfma_f32_16x16x16bf16_1k(va3, pa[sub], oa[3], 0, 0, 0);
      ob[0] = __builtin_amdgcn_mfma_f32_16x16x16bf16_1k(va0, pb[sub], ob[0], 0, 0, 0);
      ob[1] = __builtin_amdgcn_mfma_f32_16x16x16bf16_1k(va1, pb[sub], ob[1], 0, 0, 0);
      ob[2] = __builtin_amdgcn_mfma_f32_16x16x16bf16_1k(va2, pb[sub], ob[2], 0, 0, 0);
      ob[3] = __builtin_amdgcn_mfma_f32_16x16x16bf16_1k(va3, pb[sub], ob[3], 0, 0, 0);
      __builtin_amdgcn_s_setprio(0);
    }
  }

  float lta = lsa + __shfl_xor(lsa, 16);
  lta += __shfl_xor(lta, 32);
  float ltb = lsb + __shfl_xor(lsb, 16);
  ltb += __shfl_xor(ltb, 32);
  float inva = 1.0f / lta;
  float invb = 1.0f / ltb;
  u16* orowa = AO + base + (size_t)(q0 + lr) * 1024;
  u16* orowb = orowa + 16 * 1024;
#pragma unroll
  for (int c = 0; c < 4; c++) {
    u32x2 pka, pkb;
    pka[0] = cvtpk(oa[c][0] * inva, oa[c][1] * inva);
    pka[1] = cvtpk(oa[c][2] * inva, oa[c][3] * inva);
    *(u32x2*)&orowa[c * 16 + lg * 4] = pka;
    pkb[0] = cvtpk(ob[c][0] * invb, ob[c][1] * invb);
    pkb[1] = cvtpk(ob[c][2] * invb, ob[c][3] * invb);
    *(u32x2*)&orowb[c * 16 + lg * 4] = pkb;
  }
}

extern "C" void kernel_launch(void* const* d_in, const int* in_sizes, int n_in,
                              void* d_out, int out_size, void* d_ws, size_t ws_size,
                              hipStream_t stream) {
  const float* x = (const float*)d_in[0];
  const float* wq = (const float*)d_in[1];
  const float* wk = (const float*)d_in[2];
  const float* wv = (const float*)d_in[3];
  const float* wo = (const float*)d_in[4];

  char* ws = (char*)d_ws;
  u16* xb  = (u16*)(ws);
  u16* wqb = (u16*)(ws + 8388608);
  u16* wkb = (u16*)(ws + 10485760);
  u16* wvb = (u16*)(ws + 12582912);
  u16* wob = (u16*)(ws + 14680064);
  u16* Qb  = (u16*)(ws + 16777216);
  u16* Kb  = (u16*)(ws + 25165824);
  u16* Vb  = (u16*)(ws + 33554432);
  u16* AO  = (u16*)(ws + 41943040);

  k_cast5<<<8192, 256, 0, stream>>>(x, wq, wk, wv, wo, xb, wqb, wkb, wvb, wob);
  k_gemm<<<dim3(32, 24), 256, 0, stream>>>(xb, wqb, wkb, wvb, Qb, Kb, Vb, 0);
  k_rope<<<8192, 256, 0, stream>>>(Qb, Kb);
  k_attn<<<dim3(32, 16), 256, 0, stream>>>(Qb, Kb, Vb, AO);
  k_gemm<<<dim3(32, 8), 256, 0, stream>>>(AO, wob, wob, wob, d_out, d_out, d_out, 1);
}

// Round 6
// 118.791 us; speedup vs baseline: 1.0735x; 1.0735x over previous
//
#include <hip/hip_runtime.h>
#include <stdint.h>

typedef unsigned short u16;
typedef __attribute__((ext_vector_type(8))) short bf16x8;
typedef __attribute__((ext_vector_type(4))) short bf16x4;
typedef __attribute__((ext_vector_type(4))) float f32x4;
typedef __attribute__((ext_vector_type(4))) unsigned short u16x4;
typedef __attribute__((ext_vector_type(2))) unsigned u32x2;

#define S_ 2048
#define E_ 1024
// 0.125 (1/sqrt(64)) * log2(e): folds softmax scale + exp->exp2 into Q
#define QSCALE 0.18033688011112042f

__device__ __forceinline__ u16 f2bf(float f) {
  union { float f; unsigned u; } v; v.f = f;
  unsigned u = v.u;
  unsigned r = (u + 0x7FFFu + ((u >> 16) & 1u)) >> 16;
  return (u16)r;
}
__device__ __forceinline__ float bf2f(u16 h) {
  union { unsigned u; float f; } v; v.u = ((unsigned)h) << 16;
  return v.f;
}
__device__ __forceinline__ unsigned cvtpk(float a, float b) {
  unsigned r;
  asm("v_cvt_pk_bf16_f32 %0, %1, %2" : "=v"(r) : "v"(a), "v"(b));
  return r;
}
__device__ __forceinline__ bf16x4 pk4(float a, float b, float c, float d) {
  union { u32x2 u; bf16x4 v; } U;
  U.u[0] = cvtpk(a, b);
  U.u[1] = cvtpk(c, d);
  return U.v;
}

typedef __attribute__((address_space(3))) void lds_void;
__device__ __forceinline__ unsigned lds_off(void* p) {
  return (unsigned)(unsigned long long)(lds_void*)p;
}
__device__ __forceinline__ void glds16(const u16* g, u16* l) {
  __builtin_amdgcn_global_load_lds(
      (const __attribute__((address_space(1))) void*)g,
      (__attribute__((address_space(3))) void*)l, 16, 0, 0);
}

// ---------------- fused cast f32 -> bf16 for all 5 inputs ----------------
__global__ void k_cast5(const float* __restrict__ x,
                        const float* __restrict__ wq, const float* __restrict__ wk,
                        const float* __restrict__ wv, const float* __restrict__ wo,
                        u16* __restrict__ xb, u16* __restrict__ wqb, u16* __restrict__ wkb,
                        u16* __restrict__ wvb, u16* __restrict__ wob) {
  int i = blockIdx.x * blockDim.x + threadIdx.x;
  const float* src; u16* dst; int off;
  if (i < 1048576) { src = x; dst = xb; off = i; }
  else {
    int j = i - 1048576;
    int w = j >> 18; off = j & 262143;
    src = (w == 0) ? wq : (w == 1) ? wk : (w == 2) ? wv : wo;
    dst = (w == 0) ? wqb : (w == 1) ? wkb : (w == 2) ? wvb : wob;
  }
  float4 v = *((const float4*)src + off);
  u16x4 o;
  o.x = f2bf(v.x); o.y = f2bf(v.y); o.z = f2bf(v.z); o.w = f2bf(v.w);
  *((u16x4*)dst + off) = o;
}

// ---------------- 128x128 tile bf16 GEMM, 2-phase double-buffered LDS ----------------
__global__ __launch_bounds__(256) void k_gemm(
    const u16* __restrict__ A,
    const u16* __restrict__ W0, const u16* __restrict__ W1, const u16* __restrict__ W2,
    void* O0, void* O1, void* O2, int outF32)
{
  __shared__ __align__(16) u16 As[2][128 * 32];
  __shared__ __align__(16) u16 Ws[2][128 * 32];
  int tid = threadIdx.x;
  int wid = tid >> 6, lane = tid & 63;
  int lg = lane >> 4, lr = lane & 15;
  int wsel = blockIdx.y >> 3, nb = blockIdx.y & 7;
  const u16* W = (wsel == 0) ? W0 : ((wsel == 1) ? W1 : W2);
  void* O = (wsel == 0) ? O0 : ((wsel == 1) ? O1 : O2);
  int m0 = blockIdx.x * 128;
  int n0 = nb * 128;
  int wr = wid >> 1, wc = wid & 1;

  f32x4 acc[4][4];
#pragma unroll
  for (int m = 0; m < 4; m++)
#pragma unroll
    for (int n = 0; n < 4; n++) acc[m][n] = (f32x4){0.f, 0.f, 0.f, 0.f};

  int srow = tid >> 2;
  int schunk = (tid & 3) ^ ((tid >> 3) & 3);
  const u16* ag = A + (size_t)(m0 + srow) * 1024 + schunk * 8;
  const u16* wg = W + (size_t)(n0 + srow) * 1024 + schunk * 8;

  int buf = 0;
  glds16(ag, &As[0][tid * 8]);
  glds16(ag + 65536, &As[0][tid * 8 + 2048]);
  glds16(wg, &Ws[0][tid * 8]);
  glds16(wg + 65536, &Ws[0][tid * 8 + 2048]);
  __syncthreads();

  for (int kt = 0; kt < 1024; kt += 32) {
    if (kt + 32 < 1024) {
      glds16(ag + kt + 32, &As[buf ^ 1][tid * 8]);
      glds16(ag + kt + 32 + 65536, &As[buf ^ 1][tid * 8 + 2048]);
      glds16(wg + kt + 32, &Ws[buf ^ 1][tid * 8]);
      glds16(wg + kt + 32 + 65536, &Ws[buf ^ 1][tid * 8 + 2048]);
    }
    bf16x8 af[4], wf[4];
#pragma unroll
    for (int m = 0; m < 4; m++) {
      int row = wr * 64 + m * 16 + lr;
      af[m] = *(const bf16x8*)&As[buf][row * 32 + ((lg ^ ((row >> 1) & 3)) * 8)];
    }
#pragma unroll
    for (int n = 0; n < 4; n++) {
      int row = wc * 64 + n * 16 + lr;
      wf[n] = *(const bf16x8*)&Ws[buf][row * 32 + ((lg ^ ((row >> 1) & 3)) * 8)];
    }
    __builtin_amdgcn_s_setprio(1);
#pragma unroll
    for (int m = 0; m < 4; m++)
#pragma unroll
      for (int n = 0; n < 4; n++)
        acc[m][n] = __builtin_amdgcn_mfma_f32_16x16x32_bf16(af[m], wf[n], acc[m][n], 0, 0, 0);
    __builtin_amdgcn_s_setprio(0);
    __syncthreads();
    buf ^= 1;
  }

#pragma unroll
  for (int m = 0; m < 4; m++) {
    int gr = m0 + wr * 64 + m * 16 + lg * 4;
#pragma unroll
    for (int n = 0; n < 4; n++) {
      int gc = n0 + wc * 64 + n * 16 + lr;
#pragma unroll
      for (int r = 0; r < 4; r++) {
        if (outF32) ((float*)O)[(size_t)(gr + r) * 1024 + gc] = acc[m][n][r];
        else ((u16*)O)[(size_t)(gr + r) * 1024 + gc] = f2bf(acc[m][n][r]);
      }
    }
  }
}

// ---------------- RoPE in place; Q additionally scaled by QSCALE ----------------
__global__ void k_rope(u16* __restrict__ Q, u16* __restrict__ K) {
  int idx = blockIdx.x * blockDim.x + threadIdx.x;
  int p = idx & 511;
  int srow = idx >> 9;
  int s = srow & (S_ - 1);
  int i = p & 31;
  float ang = (float)s * exp2f(-0.415241012f * (float)i);
  float sn, c;
  __sincosf(ang, &sn, &c);
  unsigned* qp = (unsigned*)Q + idx;
  unsigned qv = *qp;
  float e = bf2f((u16)(qv & 0xffff)), o = bf2f((u16)(qv >> 16));
  float re = (e * c - o * sn) * QSCALE, ro = (e * sn + o * c) * QSCALE;
  *qp = cvtpk(re, ro);
  unsigned* kp = (unsigned*)K + idx;
  unsigned kv = *kp;
  e = bf2f((u16)(kv & 0xffff)); o = bf2f((u16)(kv >> 16));
  re = e * c - o * sn; ro = e * sn + o * c;
  *kp = cvtpk(re, ro);
}

// ---------------- causal flash attention, KVBLK=64, double-buffered LDS ----------------
// grid: x = bh, y = qb (reversed). 4 waves/block, wave owns 16 q rows.
// ONE barrier per tile: barrier -> prefetch(t+1)->regs -> compute buf[t&1]
//                       -> write regs->buf[(t+1)&1].
__global__ __launch_bounds__(256) void k_attn(
    const u16* __restrict__ Q, const u16* __restrict__ K,
    const u16* __restrict__ V, u16* __restrict__ AO)
{
  __shared__ __align__(16) u16 Ks[2][64 * 64];
  __shared__ __align__(16) u16 Vs[2][64 * 64];
  int tid = threadIdx.x;
  int wid = tid >> 6, lane = tid & 63;
  int lg = lane >> 4, lr = lane & 15;
  int bh = blockIdx.x;
  int qb = 31 - (int)blockIdx.y;
  int q0 = qb * 64 + wid * 16;
  size_t base = (size_t)(bh >> 4) * (2048u * 1024u) + (size_t)(bh & 15) * 64;

  const u16* qrow = Q + base + (size_t)(q0 + lr) * 1024 + lg * 8;
  bf16x8 qf0 = *(const bf16x8*)(qrow);
  bf16x8 qf1 = *(const bf16x8*)(qrow + 32);

  int srow = tid >> 3;
  int sch = tid & 7;
  const u16* kg = K + base + (size_t)srow * 1024 + sch * 8;
  const u16* vg = V + base + (size_t)srow * 1024 + sch * 8;
  int kwb0 = ((srow)*128 + sch * 16) ^ ((srow & 7) << 4);
  int kwb1 = ((srow + 32) * 128 + sch * 16) ^ ((srow & 7) << 4);
  int vwi0 = (srow >> 4) * 1024 + (sch >> 1) * 256 + (srow & 15) * 16 + (sch & 1) * 8;
  int vwi1 = ((srow + 32) >> 4) * 1024 + (sch >> 1) * 256 + (srow & 15) * 16 + (sch & 1) * 8;

  // prologue: tile 0 -> regs -> buf 0
  bf16x8 kr0 = *(const bf16x8*)(kg);
  bf16x8 kr1 = *(const bf16x8*)(kg + 32 * 1024);
  bf16x8 vr0 = *(const bf16x8*)(vg);
  bf16x8 vr1 = *(const bf16x8*)(vg + 32 * 1024);
  *(bf16x8*)((char*)Ks[0] + kwb0) = kr0;
  *(bf16x8*)((char*)Ks[0] + kwb1) = kr1;
  *(bf16x8*)(&Vs[0][vwi0]) = vr0;
  *(bf16x8*)(&Vs[0][vwi1]) = vr1;
  const u16* kgp = kg + 64 * 1024;
  const u16* vgp = vg + 64 * 1024;

  float m = -1e30f, lsum = 0.f;
  f32x4 o[4];
#pragma unroll
  for (int c = 0; c < 4; c++) o[c] = (f32x4){0.f, 0.f, 0.f, 0.f};

  int qg = q0 + lr;
  int ntile = qb + 1;

  for (int t = 0; t < ntile; ++t) {
    int buf = t & 1;
    __syncthreads();  // buf[t&1] writes visible; all waves done reading buf[(t+1)&1]
    if (t + 1 < ntile) {
      kr0 = *(const bf16x8*)(kgp);
      kr1 = *(const bf16x8*)(kgp + 32 * 1024);
      vr0 = *(const bf16x8*)(vgp);
      vr1 = *(const bf16x8*)(vgp + 32 * 1024);
      kgp += 64 * 1024;
      vgp += 64 * 1024;
    }
    const char* kb = (const char*)Ks[buf];
    unsigned vrd = lds_off(&Vs[buf][0]) + (unsigned)(lane * 8);

    f32x4 sv[4];
    int kv0 = t * 64;
    __builtin_amdgcn_s_setprio(1);
#pragma unroll
    for (int sub = 0; sub < 4; ++sub) {
      int row = sub * 16 + lr;
      int swz = (row & 7) << 4;
      bf16x8 kf0 = *(const bf16x8*)(kb + ((row * 128 + lg * 16) ^ swz));
      bf16x8 kf1 = *(const bf16x8*)(kb + ((row * 128 + 64 + lg * 16) ^ swz));
      f32x4 z = (f32x4){0.f, 0.f, 0.f, 0.f};
      z = __builtin_amdgcn_mfma_f32_16x16x32_bf16(kf0, qf0, z, 0, 0, 0);
      sv[sub] = __builtin_amdgcn_mfma_f32_16x16x32_bf16(kf1, qf1, z, 0, 0, 0);
    }
    __builtin_amdgcn_s_setprio(0);
    if (t == ntile - 1) {
#pragma unroll
      for (int sub = 0; sub < 4; ++sub)
#pragma unroll
        for (int j = 0; j < 4; ++j) {
          int kvg = kv0 + sub * 16 + lg * 4 + j;
          sv[sub][j] = (kvg <= qg) ? sv[sub][j] : -1e30f;
        }
    }
    float tm = fmaxf(fmaxf(fmaxf(sv[0][0], sv[0][1]), fmaxf(sv[0][2], sv[0][3])),
                     fmaxf(fmaxf(sv[1][0], sv[1][1]), fmaxf(sv[1][2], sv[1][3])));
    tm = fmaxf(tm, fmaxf(fmaxf(fmaxf(sv[2][0], sv[2][1]), fmaxf(sv[2][2], sv[2][3])),
                         fmaxf(fmaxf(sv[3][0], sv[3][1]), fmaxf(sv[3][2], sv[3][3]))));
    tm = fmaxf(tm, __shfl_xor(tm, 16));
    tm = fmaxf(tm, __shfl_xor(tm, 32));
    if (!__all(tm <= m + 8.f)) {
      float mn = fmaxf(m, tm);
      float corr = __builtin_amdgcn_exp2f(m - mn);
      m = mn;
      lsum *= corr;
#pragma unroll
      for (int c = 0; c < 4; ++c) {
        o[c][0] *= corr; o[c][1] *= corr; o[c][2] *= corr; o[c][3] *= corr;
      }
    }
    bf16x4 pb[4];
#pragma unroll
    for (int sub = 0; sub < 4; ++sub) {
      float p0 = __builtin_amdgcn_exp2f(sv[sub][0] - m);
      float p1 = __builtin_amdgcn_exp2f(sv[sub][1] - m);
      float p2 = __builtin_amdgcn_exp2f(sv[sub][2] - m);
      float p3 = __builtin_amdgcn_exp2f(sv[sub][3] - m);
      lsum += (p0 + p1) + (p2 + p3);
      pb[sub] = pk4(p0, p1, p2, p3);
    }
#pragma unroll
    for (int sub = 0; sub < 4; ++sub) {
      unsigned wa = vrd + (unsigned)(sub * 2048);
      bf16x4 va0, va1, va2, va3;
      asm volatile("ds_read_b64_tr_b16 %0, %1" : "=v"(va0) : "v"(wa));
      asm volatile("ds_read_b64_tr_b16 %0, %1 offset:512" : "=v"(va1) : "v"(wa));
      asm volatile("ds_read_b64_tr_b16 %0, %1 offset:1024" : "=v"(va2) : "v"(wa));
      asm volatile("ds_read_b64_tr_b16 %0, %1 offset:1536" : "=v"(va3) : "v"(wa));
      asm volatile("s_waitcnt lgkmcnt(0)" ::: "memory");
      __builtin_amdgcn_sched_barrier(0);
      __builtin_amdgcn_s_setprio(1);
      o[0] = __builtin_amdgcn_mfma_f32_16x16x16bf16_1k(va0, pb[sub], o[0], 0, 0, 0);
      o[1] = __builtin_amdgcn_mfma_f32_16x16x16bf16_1k(va1, pb[sub], o[1], 0, 0, 0);
      o[2] = __builtin_amdgcn_mfma_f32_16x16x16bf16_1k(va2, pb[sub], o[2], 0, 0, 0);
      o[3] = __builtin_amdgcn_mfma_f32_16x16x16bf16_1k(va3, pb[sub], o[3], 0, 0, 0);
      __builtin_amdgcn_s_setprio(0);
    }
    if (t + 1 < ntile) {  // write next tile into other buffer
      *(bf16x8*)((char*)Ks[buf ^ 1] + kwb0) = kr0;
      *(bf16x8*)((char*)Ks[buf ^ 1] + kwb1) = kr1;
      *(bf16x8*)(&Vs[buf ^ 1][vwi0]) = vr0;
      *(bf16x8*)(&Vs[buf ^ 1][vwi1]) = vr1;
    }
  }

  float lt = lsum + __shfl_xor(lsum, 16);
  lt += __shfl_xor(lt, 32);
  float inv = 1.0f / lt;
  u16* orow = AO + base + (size_t)(q0 + lr) * 1024;
#pragma unroll
  for (int c = 0; c < 4; c++) {
    u32x2 pk;
    pk[0] = cvtpk(o[c][0] * inv, o[c][1] * inv);
    pk[1] = cvtpk(o[c][2] * inv, o[c][3] * inv);
    *(u32x2*)&orow[c * 16 + lg * 4] = pk;
  }
}

extern "C" void kernel_launch(void* const* d_in, const int* in_sizes, int n_in,
                              void* d_out, int out_size, void* d_ws, size_t ws_size,
                              hipStream_t stream) {
  const float* x = (const float*)d_in[0];
  const float* wq = (const float*)d_in[1];
  const float* wk = (const float*)d_in[2];
  const float* wv = (const float*)d_in[3];
  const float* wo = (const float*)d_in[4];

  char* ws = (char*)d_ws;
  u16* xb  = (u16*)(ws);
  u16* wqb = (u16*)(ws + 8388608);
  u16* wkb = (u16*)(ws + 10485760);
  u16* wvb = (u16*)(ws + 12582912);
  u16* wob = (u16*)(ws + 14680064);
  u16* Qb  = (u16*)(ws + 16777216);
  u16* Kb  = (u16*)(ws + 25165824);
  u16* Vb  = (u16*)(ws + 33554432);
  u16* AO  = (u16*)(ws + 41943040);

  k_cast5<<<8192, 256, 0, stream>>>(x, wq, wk, wv, wo, xb, wqb, wkb, wvb, wob);
  k_gemm<<<dim3(32, 24), 256, 0, stream>>>(xb, wqb, wkb, wvb, Qb, Kb, Vb, 0);
  k_rope<<<8192, 256, 0, stream>>>(Qb, Kb);
  k_attn<<<dim3(32, 32), 256, 0, stream>>>(Qb, Kb, Vb, AO);
  k_gemm<<<dim3(32, 8), 256, 0, stream>>>(AO, wob, wob, wob, d_out, d_out, d_out, 1);
}